// Round 6
// baseline (2205.208 us; speedup 1.0000x reference)
//
#include <hip/hip_runtime.h>
#include <math.h>

// Problem constants (EnhancedVectorQuantizer): inputs (16,4096,256) f32, emb (2048,256) f32
#define NROWS  65536
#define DIM    256
#define KCODES 2048

#define Q_OFF  16777216   // NROWS*DIM; d_out layout: [0,Q_OFF) quantized_st, [Q_OFF]=loss, [Q_OFF+1]=perplexity, [Q_OFF+2..) idx as f32

// workspace byte offsets (total 294912 B)
#define WS_C      0        // 2048 f32  ||e_k||^2
#define WS_INV    8192     // 2048 f32  1/max(rownorm,1e-12)
#define WS_COUNTS 16384    // 2048 u32
#define WS_SUMS   24576    // 3 doubles: [0]=mse_sum [1]=l2_sum [2]=orth_sum
#define WS_CKMAX  24600    // 1 u32 (float bits): max_k c[k]
#define WS_X2     32768    // 65536 f32 ||x_n||^2

typedef __attribute__((address_space(1))) const void gvoid_t;
typedef __attribute__((address_space(3))) void lvoid_t;

// ---------------- init: zero accumulators (ws is poisoned 0xAA every launch) ----------------
__global__ void vq_init_kernel(unsigned* __restrict__ counts, double* __restrict__ sums,
                               int* __restrict__ ckmax) {
    int t = threadIdx.x;
    for (int k = t; k < KCODES; k += 256) counts[k] = 0u;
    if (t < 3) sums[t] = 0.0;
    if (t == 3) *ckmax = 0;            // +0.0f; c[k] > 0 so atomicMax(int) works
}

// ---------------- prep: c[k]=||e_k||^2, inv rownorm, l2 sum, ckmax ----------------
__global__ void vq_prep_kernel(const float* __restrict__ emb, float* __restrict__ c,
                               float* __restrict__ invn, double* __restrict__ sums,
                               int* __restrict__ ckmax) {
    int k = blockIdx.x;
    int lane = threadIdx.x;                       // 64 lanes
    float4 v = ((const float4*)(emb + (size_t)k * DIM))[lane];
    float s = v.x * v.x + v.y * v.y + v.z * v.z + v.w * v.w;
    #pragma unroll
    for (int off = 32; off > 0; off >>= 1) s += __shfl_down(s, off, 64);
    if (lane == 0) {
        c[k] = s;
        float rn = sqrtf(s);
        invn[k] = 1.0f / fmaxf(rn, 1e-12f);
        atomicAdd(&sums[1], (double)rn);
        atomicMax(ckmax, __float_as_int(s));      // s >= 0: int compare == float compare
    }
}

// ---------------- x2: per-row ||x||^2, serial float4 chain (bit-identical to ref order) ----------------
__global__ void vq_x2_kernel(const float* __restrict__ x, float* __restrict__ x2g) {
    int row = blockIdx.x * 256 + threadIdx.x;
    const float4* xr = (const float4*)(x + (size_t)row * DIM);
    float s = 0.f;
    for (int d4 = 0; d4 < DIM / 4; ++d4) {
        float4 v = xr[d4];
        s += v.x * v.x; s += v.y * v.y; s += v.z * v.z; s += v.w * v.w;
    }
    x2g[row] = s;
}

// ---------------- argmin: certified FMA screen + top-2 gap test ----------------
// Round-11/12 theory: round-10's VALUBusy (853us) hit the mul+add chain's issue floor
// (874us) -> instruction count is the wall. The bit-exact chain is only needed for
// argmin IDENTITY, so: screen with an FMA-contracted chain (512 ops/step, floor
// 437us), track per-row approx TOP-2 (lex order), and certify:
//   |dst_fma - dst_ref| <= B = 1.2e-4*sqrt(x2*ckmax) + 2e-6*(x2+ckmax)
//   (gamma_257 * Cauchy-Schwarz for both chains + assembly rounding; ~4x safety)
// Certification: ref winner k* has approx(k*) <= ref(k*)+B <= ref(I1)+B <= V1+2B < V2
// -> k* in {k: approx < V2} = {I1}. If V2 > V1 + 2B write idx; else write -(I1+1) ->
// vq_cleanup re-scans the row with the verbatim exact chain (expected ~2% of rows;
// top-2 gap ~0.13 vs 2B ~ 2.4e-3). counts for flagged rows added by cleanup only.
// DMA/LDS/pipeline skeleton is verbatim round-10 (proven: conflicts 0, no spill):
//   barrier-free K-loop, wave-private double-buffered B, half-step b0/b1 register
//   pipeline, source-swizzled A, region sched_barriers, vmcnt(0)-only waits.
#define BM 64

__global__ __launch_bounds__(256)
__attribute__((amdgpu_waves_per_eu(2, 2)))
void vq_argmin_kernel(const float* __restrict__ x, const float* __restrict__ emb,
                      const float* __restrict__ c, const float* __restrict__ x2g,
                      const int* __restrict__ ckm,
                      float* __restrict__ idx_f, unsigned* __restrict__ counts) {
    extern __shared__ float smem[];          // 81920 B
    float* Asl = smem;                       // 16384 floats (64 KB)
    float* Bsl = smem + 16384;               // 4096 floats (16 KB): [wave:4][buf:2][g:2][code:64][4]

    const int tid   = threadIdx.x;
    const int wave  = tid >> 6, lane = tid & 63;
    const int row_h = lane >> 3;             // 0..7: row group
    const int cq    = lane & 7;              // 0..7: code sub-index
    const int row0  = blockIdx.x * BM;

    const float4* x4 = (const float4*)x;
    const float4* e4 = (const float4*)emb;
    const float ckmax = __int_as_float(*ckm);

    // ---- A DMA (once): linear dest, source-swizzled; 16 instrs/wave ----
    #pragma unroll
    for (int dk = 0; dk < 4; ++dk)
        #pragma unroll
        for (int q = 0; q < 4; ++q) {
            int sg = wave + 4 * q;                       // segment 0..15 (4 rows each)
            int rsub = lane >> 4;                        // 0..3
            int row  = sg * 4 + rsub;
            int cc   = (lane & 15) ^ ((sg >> 1) & 7);    // (row>>3)&7 == (sg>>1)&7
            __builtin_amdgcn_global_load_lds(
                (gvoid_t*)(x4 + ((size_t)(row0 + row) * 64 + dk * 16 + cc)),
                (lvoid_t*)(Asl + dk * 4096 + sg * 256), 16, 0, 0);
        }

    // ---- B DMA step 0 (own 64 codes, dims [0,8)) ----
    #pragma unroll
    for (int g = 0; g < 2; ++g)
        __builtin_amdgcn_global_load_lds(
            (gvoid_t*)(e4 + ((size_t)(wave * 64 + lane) * 64 + g)),
            (lvoid_t*)(Bsl + wave * 1024 + g * 256), 16, 0, 0);

    // per-row ||x||^2 (rows row_h*8+j)
    float x2r[8];
    #pragma unroll
    for (int j = 0; j < 8; ++j) x2r[j] = x2g[row0 + row_h * 8 + j];

    __builtin_amdgcn_s_waitcnt(0);           // A + B0 landed
    __syncthreads();                         // A visible to all waves (only loop-entry barrier)

    // per-(thread,row) approx top-2 (lex order by (val, idx))
    float v1[8], v2[8]; int i1_[8], i2_[8];
    #pragma unroll
    for (int j = 0; j < 8; ++j) { v1[j] = 3.4e38f; v2[j] = 3.4e38f; i1_[j] = 0x7FFFFFFF; i2_[j] = 0x7FFFFFFF; }

    float acc[8][8];
    #pragma unroll
    for (int j = 0; j < 8; ++j)
        #pragma unroll
        for (int i = 0; i < 8; ++i) acc[j][i] = 0.f;

    const char* AsB = (const char*)Asl;
    const char* BsB = (const char*)Bsl;

    // pipelined B fragments + prefetched c values
    float4 b0[8], b1[8];
    float  ckr[8];

    // prologue: fill b0 with (s=0, g0) fragments
    {
        int bb = wave * 4096 + cq * 16;
        #pragma unroll
        for (int i = 0; i < 8; ++i) b0[i] = *(const float4*)(BsB + bb + i * 128);
    }

    // 256 steps = 8 kt-tiles (256 codes) x 32 dim-chunks (8 dims). NO barriers.
    for (int s = 0; s < 256; ++s) {
        const int dc = s & 31;
        const int bbyte = wave * 4096 + (s & 1) * 2048 + cq * 16;

        // ---- region 1: issue next DMA, c-prefetch, g1 B-frag reads ----
        if (s < 255) {
            int sn  = s + 1;
            int ktn = (sn >> 5) << 8;
            int d4n = (sn & 31) << 1;
            float* Bd = Bsl + wave * 1024 + (sn & 1) * 512;
            #pragma unroll
            for (int g = 0; g < 2; ++g)
                __builtin_amdgcn_global_load_lds(
                    (gvoid_t*)(e4 + ((size_t)(ktn + wave * 64 + lane) * 64 + d4n + g)),
                    (lvoid_t*)(Bd + g * 256), 16, 0, 0);
        }
        if (dc == 0) {
            int kt = (s >> 5) << 8;
            #pragma unroll
            for (int i = 0; i < 8; ++i) ckr[i] = c[kt + wave * 64 + cq + 8 * i];
        }
        #pragma unroll
        for (int i = 0; i < 8; ++i) b1[i] = *(const float4*)(BsB + bbyte + 1024 + i * 128);
        __builtin_amdgcn_sched_barrier(0);

        // ---- region 2: g0 math, FMA-contracted screen (covers b1 read latency) ----
        {
            int sl0 = ((dc << 1) & 15) ^ row_h;
            int abyte0 = (dc >> 3) * 16384 + row_h * 2048 + (sl0 << 4);
            float4 a[8];
            #pragma unroll
            for (int j = 0; j < 8; ++j) a[j] = *(const float4*)(AsB + abyte0 + j * 256);
            #pragma unroll
            for (int j = 0; j < 8; ++j)
                #pragma unroll
                for (int i = 0; i < 8; ++i)
                    acc[j][i] = fmaf(a[j].w, b0[i].w, fmaf(a[j].z, b0[i].z,
                                fmaf(a[j].y, b0[i].y, fmaf(a[j].x, b0[i].x, acc[j][i]))));
        }
        __builtin_amdgcn_sched_barrier(0);

        // ---- region 3: vmcnt(0)-only wait; next step's g0 B-frag reads ----
        if (s < 255) {
            __builtin_amdgcn_s_waitcnt(0x0F70);      // vmcnt(0), lgkm/exp unconstrained
            __builtin_amdgcn_sched_barrier(0);
            int bbn = wave * 4096 + ((s + 1) & 1) * 2048 + cq * 16;
            #pragma unroll
            for (int i = 0; i < 8; ++i) b0[i] = *(const float4*)(BsB + bbn + i * 128);
        }
        __builtin_amdgcn_sched_barrier(0);

        // ---- region 4: g1 math (covers b0 read latency) + top-2 fold ----
        {
            int sl1 = (((dc << 1) + 1) & 15) ^ row_h;
            int abyte1 = (dc >> 3) * 16384 + row_h * 2048 + (sl1 << 4);
            float4 a[8];
            #pragma unroll
            for (int j = 0; j < 8; ++j) a[j] = *(const float4*)(AsB + abyte1 + j * 256);
            #pragma unroll
            for (int j = 0; j < 8; ++j)
                #pragma unroll
                for (int i = 0; i < 8; ++i)
                    acc[j][i] = fmaf(a[j].w, b1[i].w, fmaf(a[j].z, b1[i].z,
                                fmaf(a[j].y, b1[i].y, fmaf(a[j].x, b1[i].x, acc[j][i]))));
        }
        if (dc == 31) {                          // full D done for this kt tile: fold top-2
            int kt = (s >> 5) << 8;
            #pragma unroll
            for (int i = 0; i < 8; ++i) {
                int k = kt + wave * 64 + cq + 8 * i;     // strictly ascending per thread
                #pragma unroll
                for (int j = 0; j < 8; ++j) {
                    float t = x2r[j] + ckr[i];
                    float dst = t - 2.0f * acc[j][i];
                    if (dst < v1[j]) { v2[j] = v1[j]; i2_[j] = i1_[j]; v1[j] = dst; i1_[j] = k; }
                    else if (dst < v2[j]) { v2[j] = dst; i2_[j] = k; }
                }
            }
            #pragma unroll
            for (int j = 0; j < 8; ++j)
                #pragma unroll
                for (int i = 0; i < 8; ++i) acc[j][i] = 0.f;
        }
    }

    // in-wave top-2 lex merge: row r's candidates live in lanes row_h*8 + (0..7)
    #pragma unroll
    for (int j = 0; j < 8; ++j) {
        #pragma unroll
        for (int off = 4; off > 0; off >>= 1) {
            float ov1 = __shfl_xor(v1[j], off, 64);  int oi1 = __shfl_xor(i1_[j], off, 64);
            float ov2 = __shfl_xor(v2[j], off, 64);  int oi2 = __shfl_xor(i2_[j], off, 64);
            if (ov1 < v1[j] || (ov1 == v1[j] && oi1 < i1_[j])) {
                if (v1[j] < ov2 || (v1[j] == ov2 && i1_[j] < oi2)) { v2[j] = v1[j]; i2_[j] = i1_[j]; }
                else { v2[j] = ov2; i2_[j] = oi2; }
                v1[j] = ov1; i1_[j] = oi1;
            } else {
                if (ov1 < v2[j] || (ov1 == v2[j] && oi1 < i2_[j])) { v2[j] = ov1; i2_[j] = oi1; }
            }
        }
    }
    // stash per-wave top-2 in OWN (dead) B region: [0..63] v1, [64..127] v2, [128..191] i1, [192..255] i2
    if (cq == 0) {
        float* stv = Bsl + wave * 1024;
        int*   sti = (int*)(Bsl + wave * 1024 + 128);
        #pragma unroll
        for (int j = 0; j < 8; ++j) {
            int r = row_h * 8 + j;
            stv[r] = v1[j]; stv[64 + r] = v2[j];
            sti[r] = i1_[j]; sti[64 + r] = i2_[j];
        }
    }
    __builtin_amdgcn_s_waitcnt(0);
    __syncthreads();
    if (tid < BM) {
        float V1 = Bsl[tid], V2 = Bsl[64 + tid];
        int   I1 = ((const int*)(Bsl + 128))[tid], I2 = ((const int*)(Bsl + 192))[tid];
        #pragma unroll
        for (int w = 1; w < 4; ++w) {
            const float* bw_ = Bsl + w * 1024;
            float ov1 = bw_[tid], ov2 = bw_[64 + tid];
            int   oi1 = ((const int*)(bw_ + 128))[tid], oi2 = ((const int*)(bw_ + 192))[tid];
            if (ov1 < V1 || (ov1 == V1 && oi1 < I1)) {
                if (V1 < ov2 || (V1 == ov2 && I1 < oi2)) { V2 = V1; I2 = I1; }
                else { V2 = ov2; I2 = oi2; }
                V1 = ov1; I1 = oi1;
            } else {
                if (ov1 < V2 || (ov1 == V2 && oi1 < I2)) { V2 = ov1; I2 = oi1; }
            }
        }
        float x2 = x2g[row0 + tid];
        float Bnd = 1.2e-4f * sqrtf(x2 * ckmax) + 2e-6f * (x2 + ckmax);
        if (V2 > V1 + 2.0f * Bnd) {              // certified: ref argmin == I1
            idx_f[row0 + tid] = (float)I1;
            atomicAdd(&counts[I1], 1u);
        } else {                                  // ambiguous: cleanup re-scans exactly
            idx_f[row0 + tid] = -(float)(I1 + 1);
        }
    }
}

// ---------------- cleanup: exact re-scan of flagged rows (verbatim ref chain) ----------------
// One wave per flagged row, grid-strided; lane l handles codes l, l+64, ... (32 codes).
// Exact chain: per 4-dim quad acc += ax*bx + ay*by + az*bz + aw*bw (ascending dims),
// dst = (x2 + c[k]) - 2*acc -- textually identical to the proven bit-exact formula.
// Lowest-index tie in both the per-lane scan (k ascending -> strict <) and the merge.
__global__ __launch_bounds__(256)
void vq_cleanup_kernel(const float* __restrict__ x, const float* __restrict__ emb,
                       const float* __restrict__ c, const float* __restrict__ x2g,
                       float* __restrict__ idx_f, unsigned* __restrict__ counts) {
    int wv   = (blockIdx.x * 256 + threadIdx.x) >> 6;   // global wave id, 8192 total
    int lane = threadIdx.x & 63;
    for (int row = wv; row < NROWS; row += 8192) {
        if (idx_f[row] >= 0.f) continue;
        float x2 = x2g[row];
        const float4* xr = (const float4*)(x + (size_t)row * DIM);
        float bv = 3.4e38f; int bi = 0x7FFFFFFF;
        for (int kk = 0; kk < 32; ++kk) {
            int k = lane + (kk << 6);                   // ascending per lane
            const float4* er = (const float4*)(emb + (size_t)k * DIM);
            float acc = 0.f;
            #pragma unroll 8
            for (int d4 = 0; d4 < 64; ++d4) {
                float4 a = xr[d4]; float4 b = er[d4];
                acc += a.x * b.x + a.y * b.y + a.z * b.z + a.w * b.w;
            }
            float t = x2 + c[k];
            float dst = t - 2.0f * acc;
            if (dst < bv) { bv = dst; bi = k; }
        }
        #pragma unroll
        for (int off = 32; off > 0; off >>= 1) {
            float ov = __shfl_down(bv, off, 64);
            int   oi = __shfl_down(bi, off, 64);
            if (ov < bv || (ov == bv && oi < bi)) { bv = ov; bi = oi; }
        }
        if (lane == 0) {
            idx_f[row] = (float)bi;
            atomicAdd(&counts[bi], 1u);
        }
    }
}

// ---------------- gather: quantized_st = x + (e - x) (matches ST rounding), MSE sum ----------------
__global__ void vq_gather_kernel(const float* __restrict__ x, const float* __restrict__ emb,
                                 const float* __restrict__ idx_f, float* __restrict__ outq,
                                 double* __restrict__ sums) {
    __shared__ float red[256];
    int tid = threadIdx.x;
    int q = blockIdx.x * 256 + tid;        // float4 index, 4194304 total
    int n = q >> 6;
    int d4 = (q & 63) << 2;
    int k = (int)idx_f[n];                 // small ints stored exactly in f32
    float4 e  = *(const float4*)(emb + (size_t)k * DIM + d4);
    float4 xv = *(const float4*)(x + ((size_t)n * DIM + d4));
    float d0 = e.x - xv.x, d1 = e.y - xv.y, d2 = e.z - xv.z, d3 = e.w - xv.w;
    float4 o;
    o.x = xv.x + d0; o.y = xv.y + d1; o.z = xv.z + d2; o.w = xv.w + d3;
    *(float4*)(outq + (size_t)q * 4) = o;
    red[tid] = d0 * d0 + d1 * d1 + d2 * d2 + d3 * d3;
    __syncthreads();
    for (int off = 128; off > 0; off >>= 1) {
        if (tid < off) red[tid] += red[tid + off];
        __syncthreads();
    }
    if (tid == 0) atomicAdd(&sums[0], (double)red[0]);
}

// ---------------- sim: sum |off-diagonal cosine| ----------------
#define SPAD 68
__global__ __launch_bounds__(256)
void vq_sim_kernel(const float* __restrict__ emb, const float* __restrict__ invn,
                   double* __restrict__ sums) {
    __shared__ float Ai[64][SPAD];
    __shared__ float Bj[64][SPAD];
    int bi = blockIdx.x >> 5;
    int bj = blockIdx.x & 31;
    int tid = threadIdx.x;
    int tx = tid & 15, ty = tid >> 4;

    float acc[4][4];
    #pragma unroll
    for (int j = 0; j < 4; ++j)
        #pragma unroll
        for (int i = 0; i < 4; ++i) acc[j][i] = 0.f;

    for (int dc = 0; dc < DIM; dc += 64) {
        #pragma unroll
        for (int rr = 0; rr < 4; ++rr) {
            int row = rr * 16 + ty;
            int col = tx * 4;
            int ga = bi * 64 + row, gb = bj * 64 + row;
            float4 a = *(const float4*)(emb + (size_t)ga * DIM + dc + col);
            float4 b = *(const float4*)(emb + (size_t)gb * DIM + dc + col);
            float sa = invn[ga], sb = invn[gb];
            Ai[row][col + 0] = a.x * sa; Ai[row][col + 1] = a.y * sa;
            Ai[row][col + 2] = a.z * sa; Ai[row][col + 3] = a.w * sa;
            Bj[row][col + 0] = b.x * sb; Bj[row][col + 1] = b.y * sb;
            Bj[row][col + 2] = b.z * sb; Bj[row][col + 3] = b.w * sb;
        }
        __syncthreads();
        for (int d = 0; d < 64; d += 4) {
            float4 a[4], b[4];
            #pragma unroll
            for (int j = 0; j < 4; ++j) a[j] = *(const float4*)&Ai[ty * 4 + j][d];
            #pragma unroll
            for (int i = 0; i < 4; ++i) b[i] = *(const float4*)&Bj[tx * 4 + i][d];
            #pragma unroll
            for (int j = 0; j < 4; ++j)
                #pragma unroll
                for (int i = 0; i < 4; ++i)
                    acc[j][i] += a[j].x * b[i].x + a[j].y * b[i].y
                               + a[j].z * b[i].z + a[j].w * b[i].w;
        }
        __syncthreads();
    }
    float s = 0.f;
    #pragma unroll
    for (int j = 0; j < 4; ++j)
        #pragma unroll
        for (int i = 0; i < 4; ++i) {
            int gi = bi * 64 + ty * 4 + j;
            int gj = bj * 64 + tx * 4 + i;
            if (gi != gj) s += fabsf(acc[j][i]);
        }
    float* red = &Ai[0][0];
    red[tid] = s;
    __syncthreads();
    for (int off = 128; off > 0; off >>= 1) {
        if (tid < off) red[tid] += red[tid + off];
        __syncthreads();
    }
    if (tid == 0) atomicAdd(&sums[2], (double)red[0]);
}

// ---------------- finalize: KL, perplexity, total loss ----------------
__global__ void vq_finalize_kernel(const unsigned* __restrict__ counts,
                                   const double* __restrict__ sums,
                                   float* __restrict__ out_scalars) {
    __shared__ double sred[256];
    int tid = threadIdx.x;
    double t = 0.0;
    for (int k = tid; k < KCODES; k += 256) t += (double)counts[k];
    sred[tid] = t; __syncthreads();
    for (int off = 128; off > 0; off >>= 1) {
        if (tid < off) sred[tid] += sred[tid + off];
        __syncthreads();
    }
    double total = sred[0];
    __syncthreads();

    const double eps = 1e-8, tunif = 1.0 / (double)KCODES;
    double klsum = 0.0, plogpsum = 0.0;
    for (int k = tid; k < KCODES; k += 256) {
        double p = (double)counts[k] / total;
        klsum += (p + eps) * log((p + eps) / (tunif + eps));
        if (p > 0.0) plogpsum += p * log(p);
    }
    sred[tid] = klsum; __syncthreads();
    for (int off = 128; off > 0; off >>= 1) {
        if (tid < off) sred[tid] += sred[tid + off];
        __syncthreads();
    }
    klsum = sred[0];
    __syncthreads();
    sred[tid] = plogpsum; __syncthreads();
    for (int off = 128; off > 0; off >>= 1) {
        if (tid < off) sred[tid] += sred[tid + off];
        __syncthreads();
    }
    plogpsum = sred[0];

    if (tid == 0) {
        float mse = (float)(sums[0] / (double)((size_t)NROWS * DIM));
        float vq = mse + 0.25f * mse;                       // q_latent + COST*e_latent (equal in value)
        float kl = fminf((float)klsum, 100.0f);
        float l2 = fminf((float)(sums[1] / (double)KCODES), 10.0f);
        float orth = fminf((float)(sums[2] / ((double)KCODES * (double)KCODES)), 10.0f);
        float reg = l2 + orth;
        float total_loss = fminf(vq + 0.1f * kl + 0.01f * reg, 100.0f);
        out_scalars[0] = total_loss;
        out_scalars[1] = (float)exp(-plogpsum);
    }
}

extern "C" void kernel_launch(void* const* d_in, const int* in_sizes, int n_in,
                              void* d_out, int out_size, void* d_ws, size_t ws_size,
                              hipStream_t stream) {
    const float* x   = (const float*)d_in[0];   // (16,4096,256) f32
    const float* emb = (const float*)d_in[1];   // (2048,256)   f32
    float* out = (float*)d_out;

    char* ws = (char*)d_ws;
    float*    c      = (float*)(ws + WS_C);
    float*    invn   = (float*)(ws + WS_INV);
    unsigned* counts = (unsigned*)(ws + WS_COUNTS);
    double*   sums   = (double*)(ws + WS_SUMS);
    int*      ckmax  = (int*)(ws + WS_CKMAX);
    float*    x2g    = (float*)(ws + WS_X2);

    float* outq        = out;                 // quantized_st
    float* out_scalars = out + Q_OFF;         // loss, perplexity
    float* idx_f       = out + Q_OFF + 2;     // idx as float

    vq_init_kernel<<<1, 256, 0, stream>>>(counts, sums, ckmax);
    vq_prep_kernel<<<KCODES, 64, 0, stream>>>(emb, c, invn, sums, ckmax);
    vq_x2_kernel<<<NROWS / 256, 256, 0, stream>>>(x, x2g);
    vq_argmin_kernel<<<NROWS / BM, 256, 81920, stream>>>(x, emb, c, x2g, ckmax, idx_f, counts);
    vq_cleanup_kernel<<<2048, 256, 0, stream>>>(x, emb, c, x2g, idx_f, counts);
    vq_gather_kernel<<<(NROWS * DIM / 4) / 256, 256, 0, stream>>>(x, emb, idx_f, outq, sums);
    vq_sim_kernel<<<(KCODES / 64) * (KCODES / 64), 256, 0, stream>>>(emb, invn, sums);
    vq_finalize_kernel<<<1, 256, 0, stream>>>(counts, sums, out_scalars);
}

// Round 8
// 980.354 us; speedup vs baseline: 2.2494x; 2.2494x over previous
//
#include <hip/hip_runtime.h>
#include <math.h>

// Problem constants (EnhancedVectorQuantizer): inputs (16,4096,256) f32, emb (2048,256) f32
#define NROWS  65536
#define DIM    256
#define KCODES 2048

#define Q_OFF  16777216   // NROWS*DIM; d_out layout: [0,Q_OFF) quantized_st, [Q_OFF]=loss, [Q_OFF+1]=perplexity, [Q_OFF+2..) idx as f32
// scratch inside the (dead-until-gather) quantized region:
//   eh  f16[2048*256]  at byte 0        (1 MB)
//   esh f16[2048*256]  at byte 1<<20    (1 MB)  -- 1024*(e - eh) in f16
//   flaglist int[65536] at byte 2<<20   (256 KB)

// workspace byte offsets (total 294912 B)
#define WS_C       0       // 2048 f32  ||e_k||^2
#define WS_INV     8192    // 2048 f32  1/max(rownorm,1e-12)
#define WS_COUNTS  16384   // 2048 u32
#define WS_SUMS    24576   // 3 doubles
#define WS_CKMAX   24600   // 1 u32 (float bits): max_k c[k]
#define WS_FLAGCNT 24604   // 1 u32
#define WS_X2      32768   // 65536 f32 ||x_n||^2

typedef __attribute__((address_space(1))) const void gvoid_t;
typedef __attribute__((address_space(3))) void lvoid_t;

typedef _Float16 half8 __attribute__((ext_vector_type(8)));
typedef _Float16 half4 __attribute__((ext_vector_type(4)));
typedef float    f32x4 __attribute__((ext_vector_type(4)));

// ---------------- init ----------------
__global__ void vq_init_kernel(unsigned* __restrict__ counts, double* __restrict__ sums,
                               int* __restrict__ ckmax, unsigned* __restrict__ flagcnt) {
    int t = threadIdx.x;
    for (int k = t; k < KCODES; k += 256) counts[k] = 0u;
    if (t < 3) sums[t] = 0.0;
    if (t == 3) *ckmax = 0;
    if (t == 4) *flagcnt = 0u;
}

// ---------------- prep: c, invn, l2 sum, ckmax, f16 split of emb ----------------
__global__ void vq_prep_kernel(const float* __restrict__ emb, float* __restrict__ c,
                               float* __restrict__ invn, double* __restrict__ sums,
                               int* __restrict__ ckmax,
                               _Float16* __restrict__ eh, _Float16* __restrict__ esh) {
    int k = blockIdx.x;
    int lane = threadIdx.x;                       // 64 lanes
    float4 v = ((const float4*)(emb + (size_t)k * DIM))[lane];
    // f16 split: e = he + hs/1024 (+O(2^-22))
    half4 he, hs;
    {
        _Float16 h0 = (_Float16)v.x; hs[0] = (_Float16)((v.x - (float)h0) * 1024.0f); he[0] = h0;
        _Float16 h1 = (_Float16)v.y; hs[1] = (_Float16)((v.y - (float)h1) * 1024.0f); he[1] = h1;
        _Float16 h2 = (_Float16)v.z; hs[2] = (_Float16)((v.z - (float)h2) * 1024.0f); he[2] = h2;
        _Float16 h3 = (_Float16)v.w; hs[3] = (_Float16)((v.w - (float)h3) * 1024.0f); he[3] = h3;
    }
    *(half4*)(eh  + (size_t)k * DIM + lane * 4) = he;
    *(half4*)(esh + (size_t)k * DIM + lane * 4) = hs;

    float s = v.x * v.x + v.y * v.y + v.z * v.z + v.w * v.w;
    #pragma unroll
    for (int off = 32; off > 0; off >>= 1) s += __shfl_down(s, off, 64);
    if (lane == 0) {
        c[k] = s;
        float rn = sqrtf(s);
        invn[k] = 1.0f / fmaxf(rn, 1e-12f);
        atomicAdd(&sums[1], (double)rn);
        atomicMax(ckmax, __float_as_int(s));      // s >= 0: int compare == float compare
    }
}

// ---------------- x2: per-row ||x||^2, serial float4 chain (bit-identical to ref order) ----------------
__global__ void vq_x2_kernel(const float* __restrict__ x, float* __restrict__ x2g) {
    int row = blockIdx.x * 256 + threadIdx.x;
    const float4* xr = (const float4*)(x + (size_t)row * DIM);
    float s = 0.f;
    for (int d4 = 0; d4 < DIM / 4; ++d4) {
        float4 v = xr[d4];
        s += v.x * v.x; s += v.y * v.y; s += v.z * v.z; s += v.w * v.w;
    }
    x2g[row] = s;
}

// ---------------- screen: f16-MFMA distance screen with certified top-2 gap test ----------------
// dot = sum(xh*eh) + 2^-10*( sum(xh*es') + sum(xr'*eh) ), xh=f16(x), xr'=f16(1024(x-xh)).
// |screen_dst - exact_chain_dst| <= B = 1e-4*sqrt(x2*ckmax) + 5e-4  (f16-split truncation
// ~3e-7*CS + fp32 accum gamma ~1.6e-5*CS + exact chain's own gamma_257 ~1.5e-5*CS + finals;
// ~3x margin). If V2 > V1 + 2B the exact argmin == I1: exact winner k* has
// screen(k*) <= exact(k*)+B <= exact(I1)+B <= V1+2B < V2 -> k* = I1. Value-ties between
// DISTINCT codes give V2==V1 -> flagged (conservative). Flagged rows -> compacted list ->
// cleanup re-scans with the verbatim exact chain. counts: certified here, flagged in cleanup.
// ROUND-8 FIX: the r7 top-2 butterfly merge treated the post-exchange SELF-duplicate
// (ov1==v1 && oi1==i1) as a value tie -> v2=v1 -> 100% flag rate. Correct merge is
// index-aware: same-winner -> v2=min(v2,ov2); else lex winners, loser v1 joins v2 pool.
// MFMA layouts (gfx950 16x16x32 f16): A lane: row=lane&15, k=(lane>>4)*8+j. B lane: col=lane&15,
// same k. D (verified m89): col=lane&15, row=(lane>>4)*4+reg.
// Block: 64 rows, wave w owns rows [w*16,w*16+16). B tiles (16 codes x 256 dims, f16 main+res =
// 16KB) shared across waves, double-buffered (32KB LDS), staged k-major so ds_read is lane*16
// consecutive (bank-perfect). s_waitcnt(0) before each barrier (proven pattern).
__global__ __launch_bounds__(256)
void vq_screen_kernel(const float* __restrict__ x,
                      const _Float16* __restrict__ eh, const _Float16* __restrict__ esh,
                      const float* __restrict__ c, const float* __restrict__ x2g,
                      const int* __restrict__ ckm,
                      float* __restrict__ idx_f, unsigned* __restrict__ counts,
                      unsigned* __restrict__ flagcnt, int* __restrict__ flaglist) {
    extern __shared__ char smem[];               // 32768 B: 2 bufs x (8KB eh-tile + 8KB esh-tile)
    const int tid   = threadIdx.x;
    const int wave  = tid >> 6, lane = tid & 63;
    const int cslot = lane & 15, g = lane >> 4;  // code slot / k-group
    const int row0  = blockIdx.x * 64;
    const float ckmax = __int_as_float(*ckm);

    // ---- A fragments: 16 rows x 256 dims, split f16, built in-register (one-time) ----
    half8 a[8], ar[8];
    {
        const float* xrow = x + (size_t)(row0 + wave * 16 + cslot) * DIM + g * 8;
        #pragma unroll
        for (int kk = 0; kk < 8; ++kk)
            #pragma unroll
            for (int j = 0; j < 8; ++j) {
                float xv = xrow[kk * 32 + j];
                _Float16 h = (_Float16)xv;
                a[kk][j]  = h;
                ar[kk][j] = (_Float16)((xv - (float)h) * 1024.0f);
            }
    }
    // x2 of the 4 D-rows this lane folds
    float x2f[4];
    #pragma unroll
    for (int r = 0; r < 4; ++r) x2f[r] = x2g[row0 + wave * 16 + g * 4 + r];

    // ---- stage tile 0 into buf 0 ----
    {
        const char* ehB  = (const char*)eh;
        const char* eshB = (const char*)esh;
        size_t rowb = (size_t)cslot * 512 + g * 16;
        #pragma unroll
        for (int q = 0; q < 4; ++q) {
            int m = wave * 4 + q;                // 0..15
            if (m < 8)
                __builtin_amdgcn_global_load_lds((gvoid_t*)(ehB + rowb + m * 64),
                                                 (lvoid_t*)(smem + m * 1024), 16, 0, 0);
            else
                __builtin_amdgcn_global_load_lds((gvoid_t*)(eshB + rowb + (m - 8) * 64),
                                                 (lvoid_t*)(smem + 8192 + (m - 8) * 1024), 16, 0, 0);
        }
    }
    __builtin_amdgcn_s_waitcnt(0);
    __syncthreads();

    float v1[4], v2[4]; int i1[4];
    #pragma unroll
    for (int r = 0; r < 4; ++r) { v1[r] = 3.4e38f; v2[r] = 3.4e38f; i1[r] = 0x7FFFFFFF; }

    for (int kt = 0; kt < 128; ++kt) {
        const int cur = kt & 1;
        // stage next tile into the other buffer
        if (kt < 127) {
            const char* ehB  = (const char*)eh;
            const char* eshB = (const char*)esh;
            size_t rowb = (size_t)((kt + 1) * 16 + cslot) * 512 + g * 16;
            char* dst = smem + (cur ^ 1) * 16384;
            #pragma unroll
            for (int q = 0; q < 4; ++q) {
                int m = wave * 4 + q;
                if (m < 8)
                    __builtin_amdgcn_global_load_lds((gvoid_t*)(ehB + rowb + m * 64),
                                                     (lvoid_t*)(dst + m * 1024), 16, 0, 0);
                else
                    __builtin_amdgcn_global_load_lds((gvoid_t*)(eshB + rowb + (m - 8) * 64),
                                                     (lvoid_t*)(dst + 8192 + (m - 8) * 1024), 16, 0, 0);
            }
        }
        float ck = c[kt * 16 + cslot];

        const char* Bc = smem + cur * 16384 + lane * 16;
        f32x4 accm = {0.f, 0.f, 0.f, 0.f};
        f32x4 accc = {0.f, 0.f, 0.f, 0.f};
        #pragma unroll
        for (int kk = 0; kk < 8; ++kk) {
            half8 be = *(const half8*)(Bc + kk * 1024);
            half8 bs = *(const half8*)(Bc + 8192 + kk * 1024);
            accm = __builtin_amdgcn_mfma_f32_16x16x32_f16(a[kk],  be, accm, 0, 0, 0);
            accc = __builtin_amdgcn_mfma_f32_16x16x32_f16(a[kk],  bs, accc, 0, 0, 0);
            accc = __builtin_amdgcn_mfma_f32_16x16x32_f16(ar[kk], be, accc, 0, 0, 0);
        }
        int k = kt * 16 + cslot;                 // strictly ascending per lane
        #pragma unroll
        for (int r = 0; r < 4; ++r) {
            float dot = accm[r] + accc[r] * 0.0009765625f;   // 2^-10 exact
            float dst = (x2f[r] + ck) - 2.0f * dot;
            if (dst < v1[r]) { v2[r] = v1[r]; v1[r] = dst; i1[r] = k; }
            else if (dst < v2[r]) { v2[r] = dst; }
        }
        __builtin_amdgcn_s_waitcnt(0);           // own DMA drained before barrier (proven)
        __syncthreads();
    }

    // merge top-2 across the 16 lanes of each D-row group (xor 8,4,2,1 stays in group).
    // Index-aware set merge (r8 fix): self/same-winner -> combine v2s only; else lex
    // winners and the loser's v1 enters the v2 pool. Distinct-code value ties -> v2==v1.
    #pragma unroll
    for (int r = 0; r < 4; ++r) {
        #pragma unroll
        for (int off = 8; off > 0; off >>= 1) {
            float ov1 = __shfl_xor(v1[r], off, 64);
            int   oi1 = __shfl_xor(i1[r], off, 64);
            float ov2 = __shfl_xor(v2[r], off, 64);
            if (oi1 == i1[r]) {
                v2[r] = fminf(v2[r], ov2);
            } else if (ov1 < v1[r] || (ov1 == v1[r] && oi1 < i1[r])) {
                v2[r] = fminf(fminf(v1[r], v2[r]), ov2);
                v1[r] = ov1; i1[r] = oi1;
            } else {
                v2[r] = fminf(fminf(ov1, v2[r]), ov2);
            }
        }
    }
    if (cslot == 0) {
        #pragma unroll
        for (int r = 0; r < 4; ++r) {
            int row = row0 + wave * 16 + g * 4 + r;
            float x2 = x2f[r];
            float Bnd = 1.0e-4f * sqrtf(x2 * ckmax) + 5e-4f;
            if (v2[r] > v1[r] + 2.0f * Bnd) {    // certified: exact argmin == i1
                idx_f[row] = (float)i1[r];
                atomicAdd(&counts[i1[r]], 1u);
            } else {
                idx_f[row] = -1.0f;
                unsigned p = atomicAdd(flagcnt, 1u);
                flaglist[p] = row;
            }
        }
    }
}

// ---------------- cleanup: exact re-scan of flagged rows (verbatim ref chain), staged tiles ----------------
// 4 waves/block, wave owns one flagged row (from compacted list). Per 64-code tile: stage emb
// tile coalesced into LDS with rotate swizzle (slot s of code row holds chunk (s+code)&63 ->
// read of chunk c4 at slot (c4-code)&63 is bank-balanced; DMA source is a rotation of the row ->
// same cache lines as linear = coalesced). Lane l owns code l of the tile; serial ascending
// 4-dim chain, textually identical to the proven exact formula. Lowest-index ties throughout.
__global__ __launch_bounds__(256)
void vq_cleanup_kernel(const float* __restrict__ x, const float* __restrict__ emb,
                       const float* __restrict__ c, const float* __restrict__ x2g,
                       const unsigned* __restrict__ flagcnt, const int* __restrict__ flaglist,
                       float* __restrict__ idx_f, unsigned* __restrict__ counts) {
    extern __shared__ float sm[];                // 16384 (Et, 64KB) + 1024 (Xs, 4KB) floats
    float* Et = sm;
    float* Xs = sm + 16384;
    const int tid = threadIdx.x;
    const int wave = tid >> 6, lane = tid & 63;
    unsigned cnt = *flagcnt;
    if (cnt == 0u) return;
    const float4* x4 = (const float4*)x;
    const float4* e4 = (const float4*)emb;

    for (unsigned base = blockIdx.x * 4u; base < cnt; base += gridDim.x * 4u) {
        unsigned ent = base + (unsigned)wave;
        bool valid = ent < cnt;
        if (!valid) ent = cnt - 1u;
        int row = flaglist[ent];
        float x2 = x2g[row];
        // stage own row (1KB) into Xs[wave]
        __builtin_amdgcn_global_load_lds((gvoid_t*)(x4 + (size_t)row * 64 + lane),
                                         (lvoid_t*)(Xs + wave * 256), 16, 0, 0);
        float bv = 3.4e38f; int bi = 0x7FFFFFFF;
        const char* XsB = (const char*)(Xs + wave * 256);
        const char* EtB = (const char*)Et;
        for (int t = 0; t < 32; ++t) {
            // stage 64-code tile: wave stages codes wave*16..+16, rotate-swizzled source
            #pragma unroll
            for (int q = 0; q < 16; ++q) {
                int code = wave * 16 + q;
                int sc = (lane + code) & 63;
                __builtin_amdgcn_global_load_lds(
                    (gvoid_t*)(e4 + ((size_t)(t * 64 + code)) * 64 + sc),
                    (lvoid_t*)(Et + code * 256), 16, 0, 0);
            }
            __builtin_amdgcn_s_waitcnt(0);
            __syncthreads();
            int k = t * 64 + lane;               // ascending per lane over t
            float ckv = c[k];
            float acc = 0.f;
            #pragma unroll 8
            for (int c4 = 0; c4 < 64; ++c4) {
                float4 av = *(const float4*)(XsB + c4 * 16);
                float4 bvv = *(const float4*)(EtB + lane * 1024 + (((c4 - lane) & 63) << 4));
                acc += av.x * bvv.x + av.y * bvv.y + av.z * bvv.z + av.w * bvv.w;
            }
            float tt = x2 + ckv;                 // matches reference eval order
            float dst = tt - 2.0f * acc;         // *2 exact
            if (dst < bv) { bv = dst; bi = k; }
            __syncthreads();                     // reads done before next stage overwrites
        }
        // wave lex-min reduce (ties -> lowest index)
        #pragma unroll
        for (int off = 32; off > 0; off >>= 1) {
            float ov = __shfl_xor(bv, off, 64);
            int   oi = __shfl_xor(bi, off, 64);
            if (ov < bv || (ov == bv && oi < bi)) { bv = ov; bi = oi; }
        }
        if (lane == 0 && valid) {
            idx_f[row] = (float)bi;
            atomicAdd(&counts[bi], 1u);
        }
    }
}

// ---------------- gather: quantized_st = x + (e - x), MSE sum ----------------
__global__ void vq_gather_kernel(const float* __restrict__ x, const float* __restrict__ emb,
                                 const float* __restrict__ idx_f, float* __restrict__ outq,
                                 double* __restrict__ sums) {
    __shared__ float red[256];
    int tid = threadIdx.x;
    int q = blockIdx.x * 256 + tid;        // float4 index, 4194304 total
    int n = q >> 6;
    int d4 = (q & 63) << 2;
    int k = (int)idx_f[n];                 // small ints stored exactly in f32
    float4 e  = *(const float4*)(emb + (size_t)k * DIM + d4);
    float4 xv = *(const float4*)(x + ((size_t)n * DIM + d4));
    float d0 = e.x - xv.x, d1 = e.y - xv.y, d2 = e.z - xv.z, d3 = e.w - xv.w;
    float4 o;
    o.x = xv.x + d0; o.y = xv.y + d1; o.z = xv.z + d2; o.w = xv.w + d3;
    *(float4*)(outq + (size_t)q * 4) = o;
    red[tid] = d0 * d0 + d1 * d1 + d2 * d2 + d3 * d3;
    __syncthreads();
    for (int off = 128; off > 0; off >>= 1) {
        if (tid < off) red[tid] += red[tid + off];
        __syncthreads();
    }
    if (tid == 0) atomicAdd(&sums[0], (double)red[0]);
}

// ---------------- sim: sum |off-diagonal cosine| ----------------
#define SPAD 68
__global__ __launch_bounds__(256)
void vq_sim_kernel(const float* __restrict__ emb, const float* __restrict__ invn,
                   double* __restrict__ sums) {
    __shared__ float Ai[64][SPAD];
    __shared__ float Bj[64][SPAD];
    int bi = blockIdx.x >> 5;
    int bj = blockIdx.x & 31;
    int tid = threadIdx.x;
    int tx = tid & 15, ty = tid >> 4;

    float acc[4][4];
    #pragma unroll
    for (int j = 0; j < 4; ++j)
        #pragma unroll
        for (int i = 0; i < 4; ++i) acc[j][i] = 0.f;

    for (int dc = 0; dc < DIM; dc += 64) {
        #pragma unroll
        for (int rr = 0; rr < 4; ++rr) {
            int row = rr * 16 + ty;
            int col = tx * 4;
            int ga = bi * 64 + row, gb = bj * 64 + row;
            float4 a = *(const float4*)(emb + (size_t)ga * DIM + dc + col);
            float4 b = *(const float4*)(emb + (size_t)gb * DIM + dc + col);
            float sa = invn[ga], sb = invn[gb];
            Ai[row][col + 0] = a.x * sa; Ai[row][col + 1] = a.y * sa;
            Ai[row][col + 2] = a.z * sa; Ai[row][col + 3] = a.w * sa;
            Bj[row][col + 0] = b.x * sb; Bj[row][col + 1] = b.y * sb;
            Bj[row][col + 2] = b.z * sb; Bj[row][col + 3] = b.w * sb;
        }
        __syncthreads();
        for (int d = 0; d < 64; d += 4) {
            float4 a[4], b[4];
            #pragma unroll
            for (int j = 0; j < 4; ++j) a[j] = *(const float4*)&Ai[ty * 4 + j][d];
            #pragma unroll
            for (int i = 0; i < 4; ++i) b[i] = *(const float4*)&Bj[tx * 4 + i][d];
            #pragma unroll
            for (int j = 0; j < 4; ++j)
                #pragma unroll
                for (int i = 0; i < 4; ++i)
                    acc[j][i] += a[j].x * b[i].x + a[j].y * b[i].y
                               + a[j].z * b[i].z + a[j].w * b[i].w;
        }
        __syncthreads();
    }
    float s = 0.f;
    #pragma unroll
    for (int j = 0; j < 4; ++j)
        #pragma unroll
        for (int i = 0; i < 4; ++i) {
            int gi = bi * 64 + ty * 4 + j;
            int gj = bj * 64 + tx * 4 + i;
            if (gi != gj) s += fabsf(acc[j][i]);
        }
    float* red = &Ai[0][0];
    red[tid] = s;
    __syncthreads();
    for (int off = 128; off > 0; off >>= 1) {
        if (tid < off) red[tid] += red[tid + off];
        __syncthreads();
    }
    if (tid == 0) atomicAdd(&sums[2], (double)red[0]);
}

// ---------------- finalize: KL, perplexity, total loss ----------------
__global__ void vq_finalize_kernel(const unsigned* __restrict__ counts,
                                   const double* __restrict__ sums,
                                   float* __restrict__ out_scalars) {
    __shared__ double sred[256];
    int tid = threadIdx.x;
    double t = 0.0;
    for (int k = tid; k < KCODES; k += 256) t += (double)counts[k];
    sred[tid] = t; __syncthreads();
    for (int off = 128; off > 0; off >>= 1) {
        if (tid < off) sred[tid] += sred[tid + off];
        __syncthreads();
    }
    double total = sred[0];
    __syncthreads();

    const double eps = 1e-8, tunif = 1.0 / (double)KCODES;
    double klsum = 0.0, plogpsum = 0.0;
    for (int k = tid; k < KCODES; k += 256) {
        double p = (double)counts[k] / total;
        klsum += (p + eps) * log((p + eps) / (tunif + eps));
        if (p > 0.0) plogpsum += p * log(p);
    }
    sred[tid] = klsum; __syncthreads();
    for (int off = 128; off > 0; off >>= 1) {
        if (tid < off) sred[tid] += sred[tid + off];
        __syncthreads();
    }
    klsum = sred[0];
    __syncthreads();
    sred[tid] = plogpsum; __syncthreads();
    for (int off = 128; off > 0; off >>= 1) {
        if (tid < off) sred[tid] += sred[tid + off];
        __syncthreads();
    }
    plogpsum = sred[0];

    if (tid == 0) {
        float mse = (float)(sums[0] / (double)((size_t)NROWS * DIM));
        float vq = mse + 0.25f * mse;                       // q_latent + COST*e_latent (equal in value)
        float kl = fminf((float)klsum, 100.0f);
        float l2 = fminf((float)(sums[1] / (double)KCODES), 10.0f);
        float orth = fminf((float)(sums[2] / ((double)KCODES * (double)KCODES)), 10.0f);
        float reg = l2 + orth;
        float total_loss = fminf(vq + 0.1f * kl + 0.01f * reg, 100.0f);
        out_scalars[0] = total_loss;
        out_scalars[1] = (float)exp(-plogpsum);
    }
}

extern "C" void kernel_launch(void* const* d_in, const int* in_sizes, int n_in,
                              void* d_out, int out_size, void* d_ws, size_t ws_size,
                              hipStream_t stream) {
    const float* x   = (const float*)d_in[0];   // (16,4096,256) f32
    const float* emb = (const float*)d_in[1];   // (2048,256)   f32
    float* out = (float*)d_out;

    char* ws = (char*)d_ws;
    float*    c       = (float*)(ws + WS_C);
    float*    invn    = (float*)(ws + WS_INV);
    unsigned* counts  = (unsigned*)(ws + WS_COUNTS);
    double*   sums    = (double*)(ws + WS_SUMS);
    int*      ckmax   = (int*)(ws + WS_CKMAX);
    unsigned* flagcnt = (unsigned*)(ws + WS_FLAGCNT);
    float*    x2g     = (float*)(ws + WS_X2);

    float* outq        = out;                 // quantized_st
    float* out_scalars = out + Q_OFF;         // loss, perplexity
    float* idx_f       = out + Q_OFF + 2;     // idx as float

    // scratch in the dead quantized region (overwritten by gather afterwards)
    _Float16* eh  = (_Float16*)((char*)d_out);
    _Float16* esh = (_Float16*)((char*)d_out + (1 << 20));
    int* flaglist = (int*)((char*)d_out + (2 << 20));

    vq_init_kernel<<<1, 256, 0, stream>>>(counts, sums, ckmax, flagcnt);
    vq_prep_kernel<<<KCODES, 64, 0, stream>>>(emb, c, invn, sums, ckmax, eh, esh);
    vq_x2_kernel<<<NROWS / 256, 256, 0, stream>>>(x, x2g);
    vq_screen_kernel<<<NROWS / 64, 256, 32768, stream>>>(x, eh, esh, c, x2g, ckmax,
                                                         idx_f, counts, flagcnt, flaglist);
    vq_cleanup_kernel<<<2048, 256, 69632, stream>>>(x, emb, c, x2g, flagcnt, flaglist,
                                                    idx_f, counts);
    vq_gather_kernel<<<(NROWS * DIM / 4) / 256, 256, 0, stream>>>(x, emb, idx_f, outq, sums);
    vq_sim_kernel<<<(KCODES / 64) * (KCODES / 64), 256, 0, stream>>>(emb, invn, sums);
    vq_finalize_kernel<<<1, 256, 0, stream>>>(counts, sums, out_scalars);
}